// Round 1
// baseline (172.624 us; speedup 1.0000x reference)
//
#include <hip/hip_runtime.h>
#include <math.h>

#define BB 8
#define TT 4096
#define EE 64
#define DD 8

// ---------------------------------------------------------------------------
// Kernel 1: q = x@Wq+bq, v = x@Wv+bv, and k written directly in the
// "reshape(B,D,T)" layout: kr[b][i][j] = k[b][i*512 + (j>>3)][j&7]
//   => k[b][t][d] lands at kr offset b*D*T + (t>>9)*T + ((t&511)<<3) + d
// 32 rows per 256-thread block; thread = (row, d).
// ---------------------------------------------------------------------------
__global__ __launch_bounds__(256) void proj_kernel(
    const float* __restrict__ x,
    const float* __restrict__ Wq, const float* __restrict__ bq,
    const float* __restrict__ Wk, const float* __restrict__ bk,
    const float* __restrict__ Wv, const float* __restrict__ bv,
    float* __restrict__ q, float* __restrict__ kr, float* __restrict__ v)
{
    __shared__ float xs[32][EE + 1];   // +1 pad: kills 8-way bank conflicts
    const int tid  = threadIdx.x;
    const int row0 = blockIdx.x * 32;

    // stage 32 rows x 64 floats (2048 floats) coalesced as float4
    const float4* xg = (const float4*)(x + (size_t)row0 * EE);
    float4 a0 = xg[tid];
    float4 a1 = xg[tid + 256];
    {
        int r = tid >> 4;
        int c = (tid & 15) << 2;
        xs[r][c+0] = a0.x; xs[r][c+1] = a0.y; xs[r][c+2] = a0.z; xs[r][c+3] = a0.w;
        xs[r+16][c+0] = a1.x; xs[r+16][c+1] = a1.y; xs[r+16][c+2] = a1.z; xs[r+16][c+3] = a1.w;
    }
    __syncthreads();

    const int r = tid >> 3;   // 0..31 row within block
    const int d = tid & 7;    // 0..7 head dim
    float accq = bq[d], acck = bk[d], accv = bv[d];
#pragma unroll
    for (int e = 0; e < EE; ++e) {
        float xv = xs[r][e];
        accq = fmaf(xv, Wq[e*DD + d], accq);
        acck = fmaf(xv, Wk[e*DD + d], acck);
        accv = fmaf(xv, Wv[e*DD + d], accv);
    }
    const int grow = row0 + r;
    const int b = grow / TT;
    const int t = grow % TT;
    q[(size_t)grow*DD + d] = accq;
    v[(size_t)grow*DD + d] = accv;
    kr[(size_t)b*DD*TT + (size_t)(t>>9)*TT + ((t&511)<<3) + d] = acck;
}

// ---------------------------------------------------------------------------
// Kernel 2: flash-style causal attention with the reference's exact masking:
//   w = tril(q @ kr);  w==0 -> -inf;  softmax(w/sqrt(8));  out = w @ v
// One wave handles 4 consecutive rows (same batch); lanes split t2.
// Online softmax state per (row,lane); butterfly reduction at the end.
// ---------------------------------------------------------------------------
__global__ __launch_bounds__(256) void attn_kernel(
    const float* __restrict__ q, const float* __restrict__ kr,
    const float* __restrict__ v, float* __restrict__ out)
{
    const int lane = threadIdx.x & 63;
    const int wave = threadIdx.x >> 6;
    const int wid  = blockIdx.x * 4 + wave;
    const int r0   = wid * 4;            // first of 4 rows (global row index)
    const int b    = r0 / TT;
    const int t0   = r0 % TT;            // all 4 rows in same batch (4 | T)

    const float* qp  = q  + (size_t)r0 * DD;
    const float* krb = kr + (size_t)b * DD * TT;
    const float* vb  = v  + (size_t)b * TT * DD;

    float qreg[4][8];
#pragma unroll
    for (int rr = 0; rr < 4; ++rr)
#pragma unroll
        for (int j = 0; j < 8; ++j) qreg[rr][j] = qp[rr*8 + j];

    float m[4], l[4], o[4][8];
#pragma unroll
    for (int rr = 0; rr < 4; ++rr) {
        m[rr] = -INFINITY; l[rr] = 0.f;
#pragma unroll
        for (int j = 0; j < 8; ++j) o[rr][j] = 0.f;
    }

    const float invs  = 0.3535533905932738f;  // 1/sqrt(8)
    const int   ntile = ((t0 + 3) >> 6) + 1;  // covers t2 <= t0+3

    for (int tt = 0; tt < ntile; ++tt) {
        const int t2 = (tt << 6) + lane;      // always < T by construction
        float kk[8];
#pragma unroll
        for (int j = 0; j < 8; ++j) kk[j] = krb[j*TT + t2];  // coalesced in t2
        float4 va  = *(const float4*)(vb + (size_t)t2*8);
        float4 vb4 = *(const float4*)(vb + (size_t)t2*8 + 4);
#pragma unroll
        for (int rr = 0; rr < 4; ++rr) {
            float s = 0.f;
#pragma unroll
            for (int j = 0; j < 8; ++j) s = fmaf(qreg[rr][j], kk[j], s);
            // faithful mask: upper triangle OR exact-zero score -> -inf
            bool  valid = (t2 <= t0 + rr) && (s != 0.0f);
            float sc = valid ? s * invs : -INFINITY;
            float mn = fmaxf(m[rr], sc);
            float alpha = (mn == m[rr]) ? 1.0f : __expf(m[rr] - mn);
            float p = valid ? __expf(sc - mn) : 0.0f;
            l[rr] = fmaf(l[rr], alpha, p);
            o[rr][0] = fmaf(o[rr][0], alpha, p * va.x);
            o[rr][1] = fmaf(o[rr][1], alpha, p * va.y);
            o[rr][2] = fmaf(o[rr][2], alpha, p * va.z);
            o[rr][3] = fmaf(o[rr][3], alpha, p * va.w);
            o[rr][4] = fmaf(o[rr][4], alpha, p * vb4.x);
            o[rr][5] = fmaf(o[rr][5], alpha, p * vb4.y);
            o[rr][6] = fmaf(o[rr][6], alpha, p * vb4.z);
            o[rr][7] = fmaf(o[rr][7], alpha, p * vb4.w);
            m[rr] = mn;
        }
    }

    // cross-lane (wave64) reduction: max, rescale, sum, write
#pragma unroll
    for (int rr = 0; rr < 4; ++rr) {
        float mg = m[rr];
#pragma unroll
        for (int off = 32; off >= 1; off >>= 1)
            mg = fmaxf(mg, __shfl_xor(mg, off, 64));
        float alpha = (m[rr] == mg) ? 1.0f : __expf(m[rr] - mg);
        float lr = l[rr] * alpha;
        float oj[8];
#pragma unroll
        for (int j = 0; j < 8; ++j) oj[j] = o[rr][j] * alpha;
#pragma unroll
        for (int off = 32; off >= 1; off >>= 1) {
            lr += __shfl_xor(lr, off, 64);
#pragma unroll
            for (int j = 0; j < 8; ++j) oj[j] += __shfl_xor(oj[j], off, 64);
        }
        if (lane == 0) {
            float inv_l = 1.0f / lr;
            float4* op = (float4*)(out + (size_t)(r0 + rr) * DD);
            op[0] = make_float4(oj[0]*inv_l, oj[1]*inv_l, oj[2]*inv_l, oj[3]*inv_l);
            op[1] = make_float4(oj[4]*inv_l, oj[5]*inv_l, oj[6]*inv_l, oj[7]*inv_l);
        }
    }
}

extern "C" void kernel_launch(void* const* d_in, const int* in_sizes, int n_in,
                              void* d_out, int out_size, void* d_ws, size_t ws_size,
                              hipStream_t stream) {
    const float* x  = (const float*)d_in[0];
    const float* Wq = (const float*)d_in[1];
    const float* bq = (const float*)d_in[2];
    const float* Wk = (const float*)d_in[3];
    const float* bk = (const float*)d_in[4];
    const float* Wv = (const float*)d_in[5];
    const float* bv = (const float*)d_in[6];
    float* out = (float*)d_out;

    float* q  = (float*)d_ws;                      // B*T*D floats
    float* kr = q  + (size_t)BB*TT*DD;             // B*D*T floats
    float* v  = kr + (size_t)BB*DD*TT;             // B*T*D floats

    proj_kernel<<<BB*TT/32, 256, 0, stream>>>(x, Wq, bq, Wk, bk, Wv, bv, q, kr, v);
    attn_kernel<<<BB*TT/16, 256, 0, stream>>>(q, kr, v, out);
}

// Round 2
// 114.467 us; speedup vs baseline: 1.5081x; 1.5081x over previous
//
#include <hip/hip_runtime.h>
#include <math.h>

#define BB 8
#define TT 4096
#define EE 64
#define DD 8
// (1/sqrt(8)) * log2(e): folded into q at projection so softmax exp is v_exp_f32
#define QSCALE 0.51012604f

typedef _Float16 half8  __attribute__((ext_vector_type(8)));
typedef _Float16 half2v __attribute__((ext_vector_type(2)));
typedef float    floatx4 __attribute__((ext_vector_type(4)));

// ---------------------------------------------------------------------------
// Kernel 1: projections in fp32, outputs in f16:
//   qh[b][t][d]  = (x@Wq+bq) * QSCALE          (A.. B-operand of St-MFMA)
//   ks[b][t2][d] = kr[b][d][t2]  (the reference's reshape, d-contiguous rows)
//   vT[b][d'][t] : rows 0-7 = v^T, row 8 = 1.0 (softmax denominator trick),
//                  rows 9-15 = 0   (A-operand of PV-MFMA, 16-row padded)
// ---------------------------------------------------------------------------
__global__ __launch_bounds__(256) void proj_kernel(
    const float* __restrict__ x,
    const float* __restrict__ Wq, const float* __restrict__ bq,
    const float* __restrict__ Wk, const float* __restrict__ bk,
    const float* __restrict__ Wv, const float* __restrict__ bv,
    _Float16* __restrict__ qh, _Float16* __restrict__ ks, _Float16* __restrict__ vT)
{
    __shared__ float xs[32][EE + 1];
    const int tid  = threadIdx.x;
    const int row0 = blockIdx.x * 32;

    const float4* xg = (const float4*)(x + (size_t)row0 * EE);
    float4 a0 = xg[tid];
    float4 a1 = xg[tid + 256];
    {
        int r = tid >> 4;
        int c = (tid & 15) << 2;
        xs[r][c+0] = a0.x; xs[r][c+1] = a0.y; xs[r][c+2] = a0.z; xs[r][c+3] = a0.w;
        xs[r+16][c+0] = a1.x; xs[r+16][c+1] = a1.y; xs[r+16][c+2] = a1.z; xs[r+16][c+3] = a1.w;
    }
    __syncthreads();

    const int r = tid >> 3;
    const int d = tid & 7;
    float accq = bq[d], acck = bk[d], accv = bv[d];
#pragma unroll
    for (int e = 0; e < EE; ++e) {
        float xv = xs[r][e];
        accq = fmaf(xv, Wq[e*DD + d], accq);
        acck = fmaf(xv, Wk[e*DD + d], acck);
        accv = fmaf(xv, Wv[e*DD + d], accv);
    }
    const int grow = row0 + r;
    const int b = grow >> 12;       // / TT
    const int t = grow & (TT - 1);  // % TT

    qh[(size_t)grow * DD + d] = (_Float16)(accq * QSCALE);
    // ks[b][t2][dcol]: t2 = ((t&511)<<3)|d, dcol = t>>9
    ks[(size_t)b * (TT*DD) + (((size_t)((t & 511) << 3) | d) << 3) + (t >> 9)] = (_Float16)acck;
    vT[(size_t)b * (16*TT) + (size_t)d * TT + t] = (_Float16)accv;

    // ones / zeros rows of vT (re-written every launch; ws is re-poisoned)
    {
        const int bb2 = row0 >> 12;
        const int t0  = row0 & (TT - 1);
        vT[(size_t)bb2 * (16*TT) + (size_t)(8 + (tid >> 5)) * TT + t0 + (tid & 31)]
            = (tid < 32) ? (_Float16)1.0f : (_Float16)0.0f;
    }
}

// ---------------------------------------------------------------------------
// Kernel 2: MFMA flash attention, transposed-score formulation.
//   St[t2][t1] = ks_frag(A) x q_frag(B)   (16x16x32 f16, k=0..7 live)
//   softmax over t2 = in-lane (16 vals) + shfl_xor 16,32
//   O^T[d'][t1] += vT_frag(A) x P^T_frag(B) ; vT row 8 = ones => l in O^T[8]
// Wave w<2: row-tile p, t2-half w; w>=2: row-tile 255-p (pairing balances
// the causal triangle). Halves merged via LDS at the end.
// ---------------------------------------------------------------------------
__global__ __launch_bounds__(256) void attn_kernel(
    const _Float16* __restrict__ qh, const _Float16* __restrict__ ks,
    const _Float16* __restrict__ vT, float* __restrict__ out)
{
    __shared__ float   mbuf[4][64];
    __shared__ floatx4 obuf[4][64];

    const int lane = threadIdx.x & 63;
    const int wave = threadIdx.x >> 6;
    const int g = lane >> 4;
    const int n = lane & 15;

    const int blk  = blockIdx.x;
    const int bb   = blk >> 7;
    const int p    = blk & 127;
    const int tile = (wave < 2) ? p : (255 - p);
    const int half = wave & 1;
    const int r0w  = tile << 4;           // batch-local first row of 16-row tile
    const int nt   = (r0w >> 6) + 1;      // 64-wide t2 tiles needed
    const int nh   = nt >> 1;
    const int tstart = half ? nh : 0;
    const int tend   = half ? nt : nh;

    const _Float16* ksb = ks + (size_t)bb * (TT*DD);
    const _Float16* vTb = vT + (size_t)bb * (16*TT);

    // Q as B-operand: B[k=j][n] = q[r0w+n][j] for k<8 (lanes g==0), else 0.
    half8 qf;
#pragma unroll
    for (int j = 0; j < 8; ++j) qf[j] = (_Float16)0.0f;
    if (g == 0) qf = *(const half8*)(qh + ((size_t)bb * TT + r0w + n) * DD);

    floatx4 oacc = {0.f, 0.f, 0.f, 0.f};
    float m = -INFINITY;

    const int  srcA  = ((g & 1) << 5) | n;   // shuffle-transpose source lanes
    const int  srcB  = srcA + 16;
    const bool hiSub = (g & 2) != 0;

    for (int tt = tstart; tt < tend; ++tt) {
        const int t2base = tt << 6;

        // ---- St = K x Q (4 sub-tiles of 16 t2) ----
        floatx4 S[4];
#pragma unroll
        for (int s = 0; s < 4; ++s) {
            half8 ka = *(const half8*)(ksb + (size_t)(t2base + (s << 4) + n) * DD);
            S[s] = __builtin_amdgcn_mfma_f32_16x16x32_f16(
                       ka, qf, (floatx4){0.f, 0.f, 0.f, 0.f}, 0, 0, 0);
        }

        // ---- masking (tril + exact-zero -> -inf), scores are pre-scaled ----
        if (t2base + 63 <= r0w) {          // fully inside the lower triangle
#pragma unroll
            for (int s = 0; s < 4; ++s)
#pragma unroll
                for (int r = 0; r < 4; ++r)
                    if (S[s][r] == 0.0f) S[s][r] = -INFINITY;
        } else {
            const int t1v = r0w + n;
#pragma unroll
            for (int s = 0; s < 4; ++s)
#pragma unroll
                for (int r = 0; r < 4; ++r) {
                    int t2v = t2base + (s << 4) + (g << 2) + r;
                    if (t2v > t1v || S[s][r] == 0.0f) S[s][r] = -INFINITY;
                }
        }

        // ---- online softmax: row (=t1=n) max over 16 in-lane + xor16/32 ----
        float rm = S[0][0];
#pragma unroll
        for (int s = 0; s < 4; ++s)
#pragma unroll
            for (int r = 0; r < 4; ++r) rm = fmaxf(rm, S[s][r]);
        rm = fmaxf(rm, __shfl_xor(rm, 16, 64));
        rm = fmaxf(rm, __shfl_xor(rm, 32, 64));

        const float mn    = fmaxf(m, rm);
        const float msafe = fmaxf(mn, -1.0e30f);           // NaN-free -inf path
        const float alpha = __builtin_amdgcn_exp2f(m - msafe); // m==-inf -> 0
        m = mn;

        // ---- p = exp2(s - m), pack to f16 pairs (regs 0,1 / 2,3) ----
        int lo[4], hi[4];
#pragma unroll
        for (int s = 0; s < 4; ++s) {
            float p0 = __builtin_amdgcn_exp2f(S[s][0] - msafe);
            float p1 = __builtin_amdgcn_exp2f(S[s][1] - msafe);
            float p2 = __builtin_amdgcn_exp2f(S[s][2] - msafe);
            float p3 = __builtin_amdgcn_exp2f(S[s][3] - msafe);
            lo[s] = __builtin_bit_cast(int, __builtin_amdgcn_cvt_pkrtz(p0, p1));
            hi[s] = __builtin_bit_cast(int, __builtin_amdgcn_cvt_pkrtz(p2, p3));
        }

        // rescale running O^T by alpha (includes l in row 8)
#pragma unroll
        for (int r = 0; r < 4; ++r) oacc[r] *= alpha;

        // ---- PV: O^T += vT_frag x P^T_frag, 2 MFMAs of k=32 t2 ----
#pragma unroll
        for (int pv = 0; pv < 2; ++pv) {
            const int sA = pv << 1, sB = sA | 1;
            int a0 = __shfl(lo[sA], srcA, 64), b0 = __shfl(lo[sB], srcA, 64);
            int a1 = __shfl(hi[sA], srcA, 64), b1 = __shfl(hi[sB], srcA, 64);
            int a2 = __shfl(lo[sA], srcB, 64), b2 = __shfl(lo[sB], srcB, 64);
            int a3 = __shfl(hi[sA], srcB, 64), b3 = __shfl(hi[sB], srcB, 64);
            int4 wi;
            wi.x = hiSub ? b0 : a0;
            wi.y = hiSub ? b1 : a1;
            wi.z = hiSub ? b2 : a2;
            wi.w = hiSub ? b3 : a3;
            half8 pb = __builtin_bit_cast(half8, wi);
            half8 va = *(const half8*)(vTb + (size_t)n * TT + t2base + (pv << 5) + (g << 3));
            oacc = __builtin_amdgcn_mfma_f32_16x16x32_f16(va, pb, oacc, 0, 0, 0);
        }
    }

    // ---- merge the two t2-halves of each row-tile, normalize, store ----
    mbuf[wave][lane] = m;
    obuf[wave][lane] = oacc;
    __syncthreads();

    if ((wave & 1) == 0) {
        const float   m2 = mbuf[wave + 1][lane];
        const floatx4 o2 = obuf[wave + 1][lane];
        const float m12   = fmaxf(m, m2);
        const float msafe = fmaxf(m12, -1.0e30f);
        const float a1s = __builtin_amdgcn_exp2f(m  - msafe);
        const float a2s = __builtin_amdgcn_exp2f(m2 - msafe);
#pragma unroll
        for (int r = 0; r < 4; ++r) oacc[r] = oacc[r] * a1s + o2[r] * a2s;

        const float l = __shfl(oacc[0], 32 + n, 64);  // O^T[8][t1] = denominator
        const float linv = 1.0f / l;
        if (g < 2) {
            float4 res;
            res.x = oacc[0] * linv; res.y = oacc[1] * linv;
            res.z = oacc[2] * linv; res.w = oacc[3] * linv;
            *(float4*)(out + (((size_t)bb * TT + r0w + n) * DD) + (g << 2)) = res;
        }
    }
}

extern "C" void kernel_launch(void* const* d_in, const int* in_sizes, int n_in,
                              void* d_out, int out_size, void* d_ws, size_t ws_size,
                              hipStream_t stream) {
    const float* x  = (const float*)d_in[0];
    const float* Wq = (const float*)d_in[1];
    const float* bq = (const float*)d_in[2];
    const float* Wk = (const float*)d_in[3];
    const float* bk = (const float*)d_in[4];
    const float* Wv = (const float*)d_in[5];
    const float* bv = (const float*)d_in[6];
    float* out = (float*)d_out;

    _Float16* qhp = (_Float16*)d_ws;                       // B*T*D
    _Float16* ksp = qhp + (size_t)BB * TT * DD;            // B*T*D
    _Float16* vTp = ksp + (size_t)BB * TT * DD;            // B*16*T

    proj_kernel<<<BB * TT / 32, 256, 0, stream>>>(x, Wq, bq, Wk, bk, Wv, bv, qhp, ksp, vTp);
    attn_kernel<<<1024, 256, 0, stream>>>(qhp, ksp, vTp, out);
}

// Round 4
// 102.548 us; speedup vs baseline: 1.6834x; 1.1162x over previous
//
#include <hip/hip_runtime.h>
#include <math.h>

#define BB 8
#define TT 4096
#define EE 64
#define DD 8
// (1/sqrt(8)) * log2(e): folded into q so p = exp2(score) directly
#define QSCALE 0.51012604f
// fixed softmax shift, implemented as MFMA C-init; cancels in normalization
#define CSHIFT -12.0f

typedef _Float16 half8  __attribute__((ext_vector_type(8)));
typedef _Float16 half4v __attribute__((ext_vector_type(4)));
typedef float    floatx4 __attribute__((ext_vector_type(4)));

// ---------------------------------------------------------------------------
// Kernel 1: projections. Block owns 32 rows t = g*512 + tbase + j (g=0..7,
// j=0..3) so the ks "reshape" scatter becomes ONE contiguous 512-B region:
//   ks element ((t&511)*8+d)*8 + (t>>9) = tbase*64 + j*64 + d*8 + g.
// q/ks/vT all staged through LDS and stored with 16-B / 8-B coalesced stores.
//   vT rows: 0-7 = v^T, row 8 = ones (softmax denominator lives in O^T[8]).
// ---------------------------------------------------------------------------
__global__ __launch_bounds__(256) void proj_kernel(
    const float* __restrict__ x,
    const float* __restrict__ Wq, const float* __restrict__ bq,
    const float* __restrict__ Wk, const float* __restrict__ bk,
    const float* __restrict__ Wv, const float* __restrict__ bv,
    _Float16* __restrict__ qh, _Float16* __restrict__ ks, _Float16* __restrict__ vT)
{
    __shared__ float    xs[32][EE + 1];
    __shared__ _Float16 qsm[256];   // [g][j][d] == tid order
    __shared__ _Float16 ksm[256];   // [j][d][g]
    __shared__ _Float16 vsm[256];   // [d][r]

    const int tid   = threadIdx.x;
    const int blk   = blockIdx.x;
    const int b     = blk >> 7;
    const int tbase = (blk & 127) << 2;

#pragma unroll
    for (int m2 = 0; m2 < 2; ++m2) {
        int r = (tid >> 4) + (m2 << 4);
        int c = (tid & 15) << 2;
        int t = ((r >> 2) << 9) + tbase + (r & 3);
        float4 a = *(const float4*)(x + (size_t)(b * TT + t) * EE + c);
        xs[r][c+0] = a.x; xs[r][c+1] = a.y; xs[r][c+2] = a.z; xs[r][c+3] = a.w;
    }
    __syncthreads();

    const int r = tid >> 3;
    const int d = tid & 7;
    float accq = bq[d], acck = bk[d], accv = bv[d];
#pragma unroll
    for (int e = 0; e < EE; ++e) {
        float xv = xs[r][e];
        accq = fmaf(xv, Wq[e*DD + d], accq);
        acck = fmaf(xv, Wk[e*DD + d], acck);
        accv = fmaf(xv, Wv[e*DD + d], accv);
    }
    qsm[tid] = (_Float16)(accq * QSCALE);
    ksm[((r & 3) << 6) + (d << 3) + (r >> 2)] = (_Float16)acck;
    vsm[(d << 5) + r] = (_Float16)accv;
    __syncthreads();

    if (tid < 32) {
        // q: region per g is 4096 elements apart; 32 contiguous per (g)
        half8 qv = *(half8*)(qsm + tid * 8);
        *(half8*)(qh + (size_t)b*(TT*DD) + (size_t)(tid >> 2)*(512*DD)
                     + (size_t)tbase*DD + ((tid & 3) << 3)) = qv;
        // ks: one contiguous 512-B block region (identity copy of ksm)
        half8 kv = *(half8*)(ksm + tid * 8);
        *(half8*)(ks + (size_t)b*(TT*DD) + (size_t)tbase*64 + tid * 8) = kv;
    } else if (tid >= 64 && tid < 128) {
        // vT rows 0..7: 8 d-rows x 8 g-slots x 4 contiguous t each
        int idx = tid - 64, d2 = idx >> 3, g2 = idx & 7;
        half4v vv = *(half4v*)(vsm + (d2 << 5) + (g2 << 2));
        *(half4v*)(vT + (size_t)b*(16*TT) + (size_t)d2*TT + (g2 << 9) + tbase) = vv;
    } else if (tid >= 128 && tid < 136) {
        // vT row 8 = ones (denominator trick)
        int g2 = tid - 128;
        half4v ones = {(_Float16)1.0f, (_Float16)1.0f, (_Float16)1.0f, (_Float16)1.0f};
        *(half4v*)(vT + (size_t)b*(16*TT) + (size_t)8*TT + (g2 << 9) + tbase) = ones;
    }
    // vT rows 9..15 feed only discarded accumulator rows (finite poison: ok)
}

// ---------------------------------------------------------------------------
// Kernel 2: MFMA flash attention, fixed-shift softmax (no running max).
//   St[t2][t1] = MFMA(ks, q, C=-12)  -> score already shifted by -12
//   p = (S == -12 ? 0 : exp2(S)); upper triangle -> -inf -> exp2 = 0
//   O^T += MFMA(vT, P^T); vT row 8 = ones accumulates the denominator.
// Block = 512 thr = 8 waves, owns tile pair (p, 255-p): exactly 65 64-wide
// tile-items, pooled round-robin across the 8 waves; merged by LDS sum.
// ---------------------------------------------------------------------------
__global__ __launch_bounds__(512, 6) void attn_kernel(
    const _Float16* __restrict__ qh, const _Float16* __restrict__ ks,
    const _Float16* __restrict__ vT, float* __restrict__ out)
{
    __shared__ floatx4 obuf[2][8][64];

    const int lane = threadIdx.x & 63;
    const int wave = threadIdx.x >> 6;
    const int g = lane >> 4;
    const int n = lane & 15;

    const int blk = blockIdx.x;
    const int bb  = blk >> 7;
    const int p   = blk & 127;
    const int ntA = (p >> 2) + 1;
    const int ntB = ((255 - p) >> 2) + 1;
    const int total = ntA + ntB;          // always 65
    const int r0A = p << 4;
    const int r0B = (255 - p) << 4;

    const _Float16* ksb = ks + (size_t)bb * (TT*DD);
    const _Float16* vTb = vT + (size_t)bb * (16*TT);

    half8 qfA, qfB;
    {
        half8 z;
#pragma unroll
        for (int j = 0; j < 8; ++j) z[j] = (_Float16)0.0f;
        qfA = z; qfB = z;
        if (g == 0) {
            qfA = *(const half8*)(qh + ((size_t)bb*TT + r0A + n) * DD);
            qfB = *(const half8*)(qh + ((size_t)bb*TT + r0B + n) * DD);
        }
    }

    floatx4 oA = {0.f, 0.f, 0.f, 0.f};
    floatx4 oB = {0.f, 0.f, 0.f, 0.f};
    const floatx4 C12 = {CSHIFT, CSHIFT, CSHIFT, CSHIFT};

    const int  srcA  = ((g & 1) << 5) | n;   // P^T shuffle-transpose sources
    const int  srcB  = srcA + 16;
    const bool hiSub = (g & 2) != 0;

    for (int i = wave; i < total; i += 8) {
        const bool isA = i < ntA;
        const int  tt  = isA ? i : (i - ntA);
        const int  r0w = isA ? r0A : r0B;
        half8 qf; if (isA) qf = qfA; else qf = qfB;
        const int t2base = tt << 6;

        // ---- St = K x Q, accumulator pre-loaded with -12 ----
        floatx4 S[4];
#pragma unroll
        for (int s = 0; s < 4; ++s) {
            half8 ka = *(const half8*)(ksb + (size_t)(t2base + (s << 4) + n) * DD);
            S[s] = __builtin_amdgcn_mfma_f32_16x16x32_f16(ka, qf, C12, 0, 0, 0);
        }

        // ---- causal mask only on the boundary tile ----
        if (t2base + 63 > r0w) {
            const int lim = r0w + n - t2base - (g << 2);
#pragma unroll
            for (int s = 0; s < 4; ++s)
#pragma unroll
                for (int rr = 0; rr < 4; ++rr)
                    if ((s << 4) + rr > lim) S[s][rr] = -INFINITY;
        }

        // ---- p = exp2(S) (already shifted); exact-zero score -> 0 ----
        int lo[4], hi[4];
#pragma unroll
        for (int s = 0; s < 4; ++s) {
            float p0 = (S[s][0] == CSHIFT) ? 0.f : __builtin_amdgcn_exp2f(S[s][0]);
            float p1 = (S[s][1] == CSHIFT) ? 0.f : __builtin_amdgcn_exp2f(S[s][1]);
            float p2 = (S[s][2] == CSHIFT) ? 0.f : __builtin_amdgcn_exp2f(S[s][2]);
            float p3 = (S[s][3] == CSHIFT) ? 0.f : __builtin_amdgcn_exp2f(S[s][3]);
            lo[s] = __builtin_bit_cast(int, __builtin_amdgcn_cvt_pkrtz(p0, p1));
            hi[s] = __builtin_bit_cast(int, __builtin_amdgcn_cvt_pkrtz(p2, p3));
        }

        // ---- O^T += vT x P^T (denominator rides in row 8) ----
        floatx4 o;
        if (isA) o = oA; else o = oB;
#pragma unroll
        for (int pv = 0; pv < 2; ++pv) {
            const int sA = pv << 1, sB = sA | 1;
            int a0 = __shfl(lo[sA], srcA, 64), b0 = __shfl(lo[sB], srcA, 64);
            int a1 = __shfl(hi[sA], srcA, 64), b1 = __shfl(hi[sB], srcA, 64);
            int a2 = __shfl(lo[sA], srcB, 64), b2 = __shfl(lo[sB], srcB, 64);
            int a3 = __shfl(hi[sA], srcB, 64), b3 = __shfl(hi[sB], srcB, 64);
            int4 wi;
            wi.x = hiSub ? b0 : a0;
            wi.y = hiSub ? b1 : a1;
            wi.z = hiSub ? b2 : a2;
            wi.w = hiSub ? b3 : a3;
            half8 pb = __builtin_bit_cast(half8, wi);
            half8 va = *(const half8*)(vTb + (size_t)n * TT + t2base + (pv << 5) + (g << 3));
            o = __builtin_amdgcn_mfma_f32_16x16x32_f16(va, pb, o, 0, 0, 0);
        }
        if (isA) oA = o; else oB = o;
    }

    obuf[0][wave][lane] = oA;
    obuf[1][wave][lane] = oB;
    __syncthreads();

    // ---- merge: plain sum of 8 partials (fixed shift -> no rebasing) ----
    if (wave < 2) {
        floatx4 osum = {0.f, 0.f, 0.f, 0.f};
#pragma unroll
        for (int w = 0; w < 8; ++w) osum += obuf[wave][w][lane];
        const float l    = __shfl(osum[0], 32 + n, 64);  // O^T[8][t1]
        const float linv = 1.0f / l;
        const int   r0   = wave ? r0B : r0A;
        if (g < 2) {
            float4 res;
            res.x = osum[0] * linv; res.y = osum[1] * linv;
            res.z = osum[2] * linv; res.w = osum[3] * linv;
            *(float4*)(out + (((size_t)bb * TT + r0 + n) * DD) + (g << 2)) = res;
        }
    }
}

extern "C" void kernel_launch(void* const* d_in, const int* in_sizes, int n_in,
                              void* d_out, int out_size, void* d_ws, size_t ws_size,
                              hipStream_t stream) {
    const float* x  = (const float*)d_in[0];
    const float* Wq = (const float*)d_in[1];
    const float* bq = (const float*)d_in[2];
    const float* Wk = (const float*)d_in[3];
    const float* bk = (const float*)d_in[4];
    const float* Wv = (const float*)d_in[5];
    const float* bv = (const float*)d_in[6];
    float* out = (float*)d_out;

    _Float16* qhp = (_Float16*)d_ws;                       // B*T*D
    _Float16* ksp = qhp + (size_t)BB * TT * DD;            // B*T*D
    _Float16* vTp = ksp + (size_t)BB * TT * DD;            // B*16*T

    proj_kernel<<<BB * TT / 32, 256, 0, stream>>>(x, Wq, bq, Wk, bk, Wv, bv, qhp, ksp, vTp);
    attn_kernel<<<1024, 512, 0, stream>>>(qhp, ksp, vTp, out);
}